// Round 2
// baseline (991.715 us; speedup 1.0000x reference)
//
#include <hip/hip_runtime.h>
#include <hip/hip_bf16.h>
#include <hip/hip_fp16.h>
#include <math.h>

// GCN link prediction. R13: drop the second (in-bucket) counting sort and the
// CSR gather entirely. After pC, edges are contiguous per 512-node bucket;
// aggregate per-bucket with LDS fp32 accumulators (512 x 16 ch, stride-17 pad
// vs bank conflicts), edge-parallel (no degree imbalance). Degree histogram is
// folded into pA (global int atomics on the same col read); dinv computed in
// k_gemm1. gemm1 runs before pC so ebuf stays L2-resident for both agg passes.
//   deg[v] = incount(col==v)+1 ; dinv = rsqrt(deg)
//   ts[v]  = (h[v]@W)*dinv[v]          (fp16 gather tables, L2-resident)
//   h'[c]  = act(dinv[c]*(sum_{e:col=c} ts[row_e] + ts[c]) + b)
//   score  = sigmoid(dot(h2[row], h2[col]))

#define BSH 9
#define BSZ 512            // nodes per bucket -> NBUK = 196 (<= 256)
#define ASTR 17            // LDS accumulator row stride (pad vs bank conflicts)
#define MAXCH 3200         // edges per chunk (multiple of 4)
#define MAXCHUNKS 1024

// ---- Phase A: per-(chunk,bucket) histogram -> M[b][NBUK]; node degree atomics ----
__global__ __launch_bounds__(512) void pA(const int* __restrict__ col,
                                          int* __restrict__ M, int* __restrict__ degi,
                                          int E, int CH, int NBUK) {
    __shared__ int hist[256];
    const int t = threadIdx.x, b = blockIdx.x;
    if (t < 256) hist[t] = 0;
    __syncthreads();
    const int s = b * CH, e = min(E, s + CH);
    const int n4 = (e - s) >> 2;                 // CH % 4 == 0 -> 16B-aligned
    const int4* c4 = (const int4*)(col + s);
    for (int i = t; i < n4; i += 512) {
        int4 c = c4[i];
        atomicAdd(&hist[c.x >> BSH], 1); atomicAdd(&degi[c.x], 1);
        atomicAdd(&hist[c.y >> BSH], 1); atomicAdd(&degi[c.y], 1);
        atomicAdd(&hist[c.z >> BSH], 1); atomicAdd(&degi[c.z], 1);
        atomicAdd(&hist[c.w >> BSH], 1); atomicAdd(&degi[c.w], 1);
    }
    for (int i = s + (n4 << 2) + t; i < e; i += 512) {
        int c = col[i];
        atomicAdd(&hist[c >> BSH], 1);
        atomicAdd(&degi[c], 1);
    }
    __syncthreads();
    for (int i = t; i < NBUK; i += 512) M[b * NBUK + i] = hist[i];
}

// ---- Phase B1: per-bucket exclusive scan over CN chunks (CN <= 1024) ----
__global__ __launch_bounds__(1024) void pB1(int* __restrict__ M, int* __restrict__ T,
                                            int NBUK, int CN) {
    __shared__ int s[1024];
    const int t = threadIdx.x, k = blockIdx.x;
    int own = (t < CN) ? M[t * NBUK + k] : 0;
    s[t] = own;
    __syncthreads();
    for (int d = 1; d < 1024; d <<= 1) {
        int add = (t >= d) ? s[t - d] : 0;
        __syncthreads();
        s[t] += add;
        __syncthreads();
    }
    if (t < CN) M[t * NBUK + k] = s[t] - own;
    if (t == 1023) T[k] = s[1023];
}

// ---- Phase B2: exclusive scan of bucket totals -> S[0..NBUK] ----
__global__ __launch_bounds__(512) void pB2(const int* __restrict__ T, int* __restrict__ S,
                                           int NBUK) {
    __shared__ int s[512];
    const int t = threadIdx.x;
    int own = (t < NBUK) ? T[t] : 0;
    s[t] = own;
    __syncthreads();
    for (int d = 1; d < 512; d <<= 1) {
        int add = (t >= d) ? s[t - d] : 0;
        __syncthreads();
        s[t] += add;
        __syncthreads();
    }
    if (t < NBUK) S[t] = s[t] - own;
    if (t == 511) S[NBUK] = s[511];
}

// ---- Phase C: LDS-staged bucket placement -> coalesced run writes ----
__global__ __launch_bounds__(512) void pC(const int* __restrict__ row, const int* __restrict__ col,
                                          const int* __restrict__ M, const int* __restrict__ S,
                                          unsigned int* __restrict__ ebuf, int E, int CH, int NBUK) {
    __shared__ unsigned int se[MAXCH];        // chunk edges, bucket-ordered
    __shared__ unsigned short pk[MAXCH];      // bucket id per LDS slot
    __shared__ int lhist[256], lbase[256], lcur[256], gbase[256];
    const int t = threadIdx.x, b = blockIdx.x;
    if (t < 256) lhist[t] = 0;
    __syncthreads();
    const int s = b * CH, e = min(E, s + CH);
    const int cnt = e - s;
    const int n4 = cnt >> 2;
    const int4* c4 = (const int4*)(col + s);
    const int4* r4 = (const int4*)(row + s);
    for (int i = t; i < n4; i += 512) {
        int4 c = c4[i];
        atomicAdd(&lhist[c.x >> BSH], 1);
        atomicAdd(&lhist[c.y >> BSH], 1);
        atomicAdd(&lhist[c.z >> BSH], 1);
        atomicAdd(&lhist[c.w >> BSH], 1);
    }
    for (int i = (n4 << 2) + t; i < cnt; i += 512) atomicAdd(&lhist[col[s + i] >> BSH], 1);
    __syncthreads();
    {   // 256-wide exclusive scan of lhist -> lbase (scratch in lcur); threads 0-255
        int own = (t < 256) ? lhist[t] : 0;
        if (t < 256) lcur[t] = own;
        __syncthreads();
        for (int d = 1; d < 256; d <<= 1) {
            int add = (t < 256 && t >= d) ? lcur[t - d] : 0;
            __syncthreads();
            if (t < 256) lcur[t] += add;
            __syncthreads();
        }
        if (t < 256) {
            lbase[t] = lcur[t] - own;
            lcur[t] = lcur[t] - own;
        }
        __syncthreads();
        if (t < NBUK) gbase[t] = S[t] + M[b * NBUK + t] - lbase[t];
    }
    __syncthreads();
    // placement into LDS (bucket-ordered)
    for (int i = t; i < n4; i += 512) {
        int4 c = c4[i];
        int4 r = r4[i];
        int k0 = c.x >> BSH, p0 = atomicAdd(&lcur[k0], 1);
        se[p0] = ((unsigned int)(c.x & (BSZ - 1)) << 17) | (unsigned int)r.x; pk[p0] = (unsigned short)k0;
        int k1 = c.y >> BSH, p1 = atomicAdd(&lcur[k1], 1);
        se[p1] = ((unsigned int)(c.y & (BSZ - 1)) << 17) | (unsigned int)r.y; pk[p1] = (unsigned short)k1;
        int k2 = c.z >> BSH, p2 = atomicAdd(&lcur[k2], 1);
        se[p2] = ((unsigned int)(c.z & (BSZ - 1)) << 17) | (unsigned int)r.z; pk[p2] = (unsigned short)k2;
        int k3 = c.w >> BSH, p3 = atomicAdd(&lcur[k3], 1);
        se[p3] = ((unsigned int)(c.w & (BSZ - 1)) << 17) | (unsigned int)r.w; pk[p3] = (unsigned short)k3;
    }
    for (int i = (n4 << 2) + t; i < cnt; i += 512) {
        int c = col[s + i], r = row[s + i];
        int k = c >> BSH, p = atomicAdd(&lcur[k], 1);
        se[p] = ((unsigned int)(c & (BSZ - 1)) << 17) | (unsigned int)r; pk[p] = (unsigned short)k;
    }
    __syncthreads();
    // coalesced write-out: consecutive LDS slots in a bucket -> consecutive global
    for (int i = t; i < cnt; i += 512) {
        int k = pk[i];
        ebuf[gbase[k] + i] = se[i];
    }
}

// ---- GEMM1: dinv[v] = rsqrt(deg+1); ts1h[v] = half((x[v] @ W1) * dinv[v]) ----
__global__ __launch_bounds__(256) void k_gemm1(
    const float* __restrict__ x, const float* __restrict__ W1,
    const int* __restrict__ degi, float* __restrict__ dinv,
    __half* __restrict__ ts, int N) {
    __shared__ float wsT[16 * 132];
    const int tid = threadIdx.x;
    for (int idx = tid; idx < 2048; idx += 256) {
        int k = idx >> 4, c = idx & 15;
        wsT[c * 132 + k] = W1[idx];
    }
    __syncthreads();
    const int n = blockIdx.x * 256 + tid;
    if (n >= N) return;
    const float4* xr = (const float4*)(x + (size_t)n * 128);
    float acc[16];
    #pragma unroll
    for (int c = 0; c < 16; ++c) acc[c] = 0.f;
    #pragma unroll 4
    for (int k4 = 0; k4 < 32; ++k4) {
        float4 a = xr[k4];
        #pragma unroll
        for (int c = 0; c < 16; ++c) {
            const float4 w = *(const float4*)&wsT[c * 132 + k4 * 4];
            acc[c] = fmaf(a.x, w.x, fmaf(a.y, w.y, fmaf(a.z, w.z, fmaf(a.w, w.w, acc[c]))));
        }
    }
    const float dv = rsqrtf((float)degi[n] + 1.0f);
    dinv[n] = dv;
    union { __half h[16]; uint4 u[2]; } o;
    #pragma unroll
    for (int c = 0; c < 16; ++c) o.h[c] = __float2half(acc[c] * dv);
    uint4* dst = (uint4*)(ts + (size_t)n * 16);
    dst[0] = o.u[0]; dst[1] = o.u[1];
}

// Unpack one node row (2 x uint4 = 16 halves) and atomically accumulate into LDS.
#define ACCAT16(aptr, qa, qb) do {                                                         \
    float2 f_;                                                                             \
    f_ = __half22float2(*(const __half2*)&(qa).x); atomicAdd((aptr) + 0,  f_.x); atomicAdd((aptr) + 1,  f_.y); \
    f_ = __half22float2(*(const __half2*)&(qa).y); atomicAdd((aptr) + 2,  f_.x); atomicAdd((aptr) + 3,  f_.y); \
    f_ = __half22float2(*(const __half2*)&(qa).z); atomicAdd((aptr) + 4,  f_.x); atomicAdd((aptr) + 5,  f_.y); \
    f_ = __half22float2(*(const __half2*)&(qa).w); atomicAdd((aptr) + 6,  f_.x); atomicAdd((aptr) + 7,  f_.y); \
    f_ = __half22float2(*(const __half2*)&(qb).x); atomicAdd((aptr) + 8,  f_.x); atomicAdd((aptr) + 9,  f_.y); \
    f_ = __half22float2(*(const __half2*)&(qb).y); atomicAdd((aptr) + 10, f_.x); atomicAdd((aptr) + 11, f_.y); \
    f_ = __half22float2(*(const __half2*)&(qb).z); atomicAdd((aptr) + 12, f_.x); atomicAdd((aptr) + 13, f_.y); \
    f_ = __half22float2(*(const __half2*)&(qb).w); atomicAdd((aptr) + 14, f_.x); atomicAdd((aptr) + 15, f_.y); \
} while (0)

// ---- Layer-1 aggregation: one block per bucket, edge-parallel LDS fp32
//      accumulation; epilogue bias/ReLU + 16x16 W2 from LDS; writes ts2h ----
__global__ __launch_bounds__(1024) void pAgg1(
    const unsigned int* __restrict__ ebuf, const int* __restrict__ S,
    const uint4* __restrict__ tsq, const float* __restrict__ dinv,
    const float* __restrict__ b1, const float* __restrict__ W2,
    uint4* __restrict__ ts2q, int N) {
    __shared__ float acc[BSZ * ASTR];     // 34.8 KB
    __shared__ float w2s[256];
    const int t = threadIdx.x, k = blockIdx.x;
    for (int i = t; i < BSZ * ASTR; i += 1024) acc[i] = 0.f;
    if (t < 256) w2s[t] = W2[t];
    __syncthreads();
    const int s = S[k], e = S[k + 1];
    int i = s + t;
    for (; i + 1024 < e; i += 2048) {
        unsigned int w0 = ebuf[i], w1 = ebuf[i + 1024];
        const size_t r0 = (size_t)(w0 & 0x1FFFF), r1 = (size_t)(w1 & 0x1FFFF);
        uint4 qa0 = tsq[r0 << 1], qb0 = tsq[(r0 << 1) + 1];
        uint4 qa1 = tsq[r1 << 1], qb1 = tsq[(r1 << 1) + 1];
        float* a0 = &acc[(w0 >> 17) * ASTR];
        float* a1 = &acc[(w1 >> 17) * ASTR];
        ACCAT16(a0, qa0, qb0);
        ACCAT16(a1, qa1, qb1);
    }
    if (i < e) {
        unsigned int w0 = ebuf[i];
        const size_t r0 = (size_t)(w0 & 0x1FFFF);
        uint4 qa0 = tsq[r0 << 1], qb0 = tsq[(r0 << 1) + 1];
        float* a0 = &acc[(w0 >> 17) * ASTR];
        ACCAT16(a0, qa0, qb0);
    }
    __syncthreads();
    // epilogue: 2 threads per node; each computes 8 output channels
    const int lv = t >> 1, p = t & 1;
    const int v = (k << BSH) + lv;
    if (v >= N) return;
    const float dv = dinv[v];
    uint4 sa = tsq[(size_t)v << 1];
    uint4 sb = tsq[((size_t)v << 1) + 1];
    const float* ap = &acc[lv * ASTR];
    float hh[16];
    {
        float2 f_;
        f_ = __half22float2(*(const __half2*)&sa.x); hh[0]  = ap[0]  + f_.x; hh[1]  = ap[1]  + f_.y;
        f_ = __half22float2(*(const __half2*)&sa.y); hh[2]  = ap[2]  + f_.x; hh[3]  = ap[3]  + f_.y;
        f_ = __half22float2(*(const __half2*)&sa.z); hh[4]  = ap[4]  + f_.x; hh[5]  = ap[5]  + f_.y;
        f_ = __half22float2(*(const __half2*)&sa.w); hh[6]  = ap[6]  + f_.x; hh[7]  = ap[7]  + f_.y;
        f_ = __half22float2(*(const __half2*)&sb.x); hh[8]  = ap[8]  + f_.x; hh[9]  = ap[9]  + f_.y;
        f_ = __half22float2(*(const __half2*)&sb.y); hh[10] = ap[10] + f_.x; hh[11] = ap[11] + f_.y;
        f_ = __half22float2(*(const __half2*)&sb.z); hh[12] = ap[12] + f_.x; hh[13] = ap[13] + f_.y;
        f_ = __half22float2(*(const __half2*)&sb.w); hh[14] = ap[14] + f_.x; hh[15] = ap[15] + f_.y;
    }
    #pragma unroll
    for (int c = 0; c < 16; ++c) hh[c] = fmaxf(fmaf(dv, hh[c], b1[c]), 0.f);
    float o[8];
    #pragma unroll
    for (int c = 0; c < 8; ++c) o[c] = 0.f;
    const int cb = 8 * p;
    #pragma unroll
    for (int j = 0; j < 16; ++j) {
        const float hj = hh[j];
        #pragma unroll
        for (int c = 0; c < 8; ++c) o[c] = fmaf(hj, w2s[j * 16 + cb + c], o[c]);
    }
    union { __half h8[8]; uint4 u; } ov;
    #pragma unroll
    for (int c = 0; c < 8; ++c) ov.h8[c] = __float2half(dv * o[c]);
    ts2q[((size_t)v << 1) + p] = ov.u;
}

// ---- Layer-2 aggregation: same accumulate; epilogue bias only -> h2h ----
__global__ __launch_bounds__(1024) void pAgg2(
    const unsigned int* __restrict__ ebuf, const int* __restrict__ S,
    const uint4* __restrict__ tsq, const float* __restrict__ dinv,
    const float* __restrict__ b2, uint4* __restrict__ h2q, int N) {
    __shared__ float acc[BSZ * ASTR];
    const int t = threadIdx.x, k = blockIdx.x;
    for (int i = t; i < BSZ * ASTR; i += 1024) acc[i] = 0.f;
    __syncthreads();
    const int s = S[k], e = S[k + 1];
    int i = s + t;
    for (; i + 1024 < e; i += 2048) {
        unsigned int w0 = ebuf[i], w1 = ebuf[i + 1024];
        const size_t r0 = (size_t)(w0 & 0x1FFFF), r1 = (size_t)(w1 & 0x1FFFF);
        uint4 qa0 = tsq[r0 << 1], qb0 = tsq[(r0 << 1) + 1];
        uint4 qa1 = tsq[r1 << 1], qb1 = tsq[(r1 << 1) + 1];
        float* a0 = &acc[(w0 >> 17) * ASTR];
        float* a1 = &acc[(w1 >> 17) * ASTR];
        ACCAT16(a0, qa0, qb0);
        ACCAT16(a1, qa1, qb1);
    }
    if (i < e) {
        unsigned int w0 = ebuf[i];
        const size_t r0 = (size_t)(w0 & 0x1FFFF);
        uint4 qa0 = tsq[r0 << 1], qb0 = tsq[(r0 << 1) + 1];
        float* a0 = &acc[(w0 >> 17) * ASTR];
        ACCAT16(a0, qa0, qb0);
    }
    __syncthreads();
    // epilogue: 2 threads per node; thread handles its own 8 channels
    const int lv = t >> 1, p = t & 1;
    const int v = (k << BSH) + lv;
    if (v >= N) return;
    const float dv = dinv[v];
    uint4 sq = tsq[((size_t)v << 1) + p];
    const float* ap = &acc[lv * ASTR + 8 * p];
    const float* bp = b2 + 8 * p;
    union { __half h8[8]; uint4 u; } ov;
    float2 f_;
    f_ = __half22float2(*(const __half2*)&sq.x);
    ov.h8[0] = __float2half(fmaf(dv, ap[0] + f_.x, bp[0]));
    ov.h8[1] = __float2half(fmaf(dv, ap[1] + f_.y, bp[1]));
    f_ = __half22float2(*(const __half2*)&sq.y);
    ov.h8[2] = __float2half(fmaf(dv, ap[2] + f_.x, bp[2]));
    ov.h8[3] = __float2half(fmaf(dv, ap[3] + f_.y, bp[3]));
    f_ = __half22float2(*(const __half2*)&sq.z);
    ov.h8[4] = __float2half(fmaf(dv, ap[4] + f_.x, bp[4]));
    ov.h8[5] = __float2half(fmaf(dv, ap[5] + f_.y, bp[5]));
    f_ = __half22float2(*(const __half2*)&sq.w);
    ov.h8[6] = __float2half(fmaf(dv, ap[6] + f_.x, bp[6]));
    ov.h8[7] = __float2half(fmaf(dv, ap[7] + f_.y, bp[7]));
    h2q[((size_t)v << 1) + p] = ov.u;
}

// ---- Edge scores (R8/R10-proven: 1 edge/thread, no NT) ----
__global__ void k_score(const int* __restrict__ row, const int* __restrict__ col,
                        const __half* __restrict__ h2h, float* __restrict__ out, int E) {
    int e = blockIdx.x * 256 + threadIdx.x;
    if (e < E) {
        union { uint4 u[2]; __half2 h[8]; } a, b;
        const uint4* pa = (const uint4*)(h2h + (size_t)row[e] * 16);
        const uint4* pb = (const uint4*)(h2h + (size_t)col[e] * 16);
        a.u[0] = pa[0]; a.u[1] = pa[1];
        b.u[0] = pb[0]; b.u[1] = pb[1];
        float d = 0.f;
        #pragma unroll
        for (int i = 0; i < 8; ++i) {
            float2 fa = __half22float2(a.h[i]);
            float2 fb = __half22float2(b.h[i]);
            d = fmaf(fa.x, fb.x, fmaf(fa.y, fb.y, d));
        }
        out[e] = 1.0f / (1.0f + __expf(-d));
    }
}

// ---------------- Fallback (R2 atomic path) ----------------
__global__ void k_countf(const int* __restrict__ col, float* __restrict__ deg, int E) {
    int e = blockIdx.x * 256 + threadIdx.x;
    if (e < E) atomicAdd(&deg[col[e]], 1.0f);
}
__global__ void k_dinvf(float* __restrict__ dinv, int N) {
    int v = blockIdx.x * 256 + threadIdx.x;
    if (v < N) dinv[v] = rsqrtf(dinv[v] + 1.0f);
}
__global__ __launch_bounds__(256) void k_gemm1f(
    const float* __restrict__ x, const float* __restrict__ W1,
    const float* __restrict__ dinv, float* __restrict__ ts, int N) {
    __shared__ float wsT[16 * 132];
    const int tid = threadIdx.x;
    for (int idx = tid; idx < 2048; idx += 256) {
        int k = idx >> 4, c = idx & 15;
        wsT[c * 132 + k] = W1[idx];
    }
    __syncthreads();
    const int n = blockIdx.x * 256 + tid;
    if (n >= N) return;
    const float4* xr = (const float4*)(x + (size_t)n * 128);
    float acc[16];
    #pragma unroll
    for (int c = 0; c < 16; ++c) acc[c] = 0.f;
    for (int k4 = 0; k4 < 32; ++k4) {
        float4 a = xr[k4];
        #pragma unroll
        for (int c = 0; c < 16; ++c) {
            const float4 w = *(const float4*)&wsT[c * 132 + k4 * 4];
            acc[c] = fmaf(a.x, w.x, fmaf(a.y, w.y, fmaf(a.z, w.z, fmaf(a.w, w.w, acc[c]))));
        }
    }
    float dv = dinv[n];
    float4* o = (float4*)(ts + (size_t)n * 16);
    #pragma unroll
    for (int q = 0; q < 4; ++q)
        o[q] = make_float4(acc[4*q] * dv, acc[4*q+1] * dv, acc[4*q+2] * dv, acc[4*q+3] * dv);
}
__global__ void k_scatter(const int* __restrict__ row, const int* __restrict__ col,
                          const float* __restrict__ ts, float* __restrict__ acc, int E) {
    int g = blockIdx.x * 256 + threadIdx.x;
    int e = g >> 4, c = g & 15;
    if (e < E) atomicAdd(&acc[(size_t)col[e] * 16 + c], ts[(size_t)row[e] * 16 + c]);
}
__global__ void k_finalize(float* __restrict__ acc, const float* __restrict__ ts,
                           const float* __restrict__ dinv, const float* __restrict__ b,
                           int N, int relu) {
    int g = blockIdx.x * 256 + threadIdx.x;
    int v = g >> 4, c = g & 15;
    if (v < N) {
        float h = dinv[v] * (acc[g] + ts[g]) + b[c];
        if (relu) h = fmaxf(h, 0.f);
        acc[g] = h;
    }
}
__global__ __launch_bounds__(256) void k_gemm2f(
    const float* __restrict__ h1, const float* __restrict__ W2,
    const float* __restrict__ dinv, float* __restrict__ ts2, int N) {
    __shared__ float hs[16 * 17];
    __shared__ float ws2[256];
    const int tid = threadIdx.x;
    const int base = blockIdx.x * 16;
    if (tid < 64) ((float4*)ws2)[tid] = ((const float4*)W2)[tid];
    if (tid >= 64 && tid < 128) {
        int t2 = tid - 64;
        float4 v4 = ((const float4*)(h1 + (size_t)base * 16))[t2];
        float* d = &hs[(t2 >> 2) * 17 + (t2 & 3) * 4];
        d[0] = v4.x; d[1] = v4.y; d[2] = v4.z; d[3] = v4.w;
    }
    __syncthreads();
    const int r = tid >> 4, c = tid & 15;
    float a = 0.f;
    #pragma unroll
    for (int kk = 0; kk < 16; ++kk) a = fmaf(hs[r * 17 + kk], ws2[kk * 16 + c], a);
    ts2[(size_t)(base + r) * 16 + c] = a * dinv[base + r];
}
__global__ void k_scoref(const int* __restrict__ row, const int* __restrict__ col,
                         const float* __restrict__ h2, float* __restrict__ out, int E) {
    int e = blockIdx.x * 256 + threadIdx.x;
    if (e < E) {
        const float4* a = (const float4*)(h2 + (size_t)row[e] * 16);
        const float4* b = (const float4*)(h2 + (size_t)col[e] * 16);
        float d = 0.f;
        #pragma unroll
        for (int i = 0; i < 4; ++i) {
            float4 u = a[i], v = b[i];
            d += u.x * v.x + u.y * v.y + u.z * v.z + u.w * v.w;
        }
        out[e] = 1.0f / (1.0f + __expf(-d));
    }
}

extern "C" void kernel_launch(void* const* d_in, const int* in_sizes, int n_in,
                              void* d_out, int out_size, void* d_ws, size_t ws_size,
                              hipStream_t stream) {
    const float* x  = (const float*)d_in[0];
    const int*   ei = (const int*)d_in[1];
    const float* W1 = (const float*)d_in[2];
    const float* b1 = (const float*)d_in[3];
    const float* W2 = (const float*)d_in[4];
    const float* b2 = (const float*)d_in[5];

    const int N = in_sizes[0] / 128;   // 100000
    const int E = in_sizes[1] / 2;     // 3200000
    const int* row = ei;
    const int* col = ei + E;
    float* out = (float*)d_out;

    const int NBUK = (N + BSZ - 1) / BSZ;          // 196
    const int CN = (E + MAXCH - 1) / MAXCH;        // 1000 chunks
    const int CH = MAXCH;                          // 3200, multiple of 4

    char* ws = (char*)d_ws;
    size_t off = 0;
    auto alloc = [&](size_t bytes) { void* p = ws + off; off += (bytes + 255) & ~(size_t)255; return p; };
    float*  dinv  = (float*)alloc((size_t)N * 4);
    __half* ts1h  = (__half*)alloc((size_t)N * 32);    // also h2h after pAgg2
    __half* ts2h  = (__half*)alloc((size_t)N * 32);
    int*    degi  = (int*)alloc((size_t)N * 4);
    int*    M     = (int*)alloc((size_t)CN * NBUK * 4);
    int*    T     = (int*)alloc((size_t)NBUK * 4);
    int*    S     = (int*)alloc((size_t)(NBUK + 1) * 4);
    unsigned int* ebuf  = (unsigned int*)alloc((size_t)E * 4);
    const size_t need = off;    // ~21 MB at N=100k, E=3.2M

    if (N <= 131072 && NBUK <= 256 && CN <= MAXCHUNKS && ws_size >= need) {
        hipMemsetAsync(degi, 0, (size_t)N * 4, stream);
        pA <<<CN, 512, 0, stream>>>(col, M, degi, E, CH, NBUK);
        pB1<<<NBUK, 1024, 0, stream>>>(M, T, NBUK, CN);
        pB2<<<1, 512, 0, stream>>>(T, S, NBUK);
        k_gemm1<<<(N + 255) / 256, 256, 0, stream>>>(x, W1, degi, dinv, ts1h, N);
        pC <<<CN, 512, 0, stream>>>(row, col, M, S, ebuf, E, CH, NBUK);
        pAgg1<<<NBUK, 1024, 0, stream>>>(ebuf, S, (const uint4*)ts1h, dinv, b1, W2,
                                         (uint4*)ts2h, N);
        __half* h2h = ts1h;   // ts1h dead after pAgg1
        pAgg2<<<NBUK, 1024, 0, stream>>>(ebuf, S, (const uint4*)ts2h, dinv, b2,
                                         (uint4*)h2h, N);
        k_score<<<(E + 255) / 256, 256, 0, stream>>>(row, col, h2h, out, E);
    } else {
        // R2 fallback, fp32 buffers carved independently
        float* dinvF = (float*)ws;
        float* ts1F  = (float*)(ws + (size_t)N * 4);
        float* ts2F  = (float*)(ws + (size_t)N * 4 + (size_t)N * 64);
        hipMemsetAsync(dinvF, 0, (size_t)N * 4, stream);
        hipMemsetAsync(ts2F, 0, (size_t)N * 64, stream);
        k_countf<<<(E + 255) / 256, 256, 0, stream>>>(col, dinvF, E);
        k_dinvf<<<(N + 255) / 256, 256, 0, stream>>>(dinvF, N);
        k_gemm1f<<<(N + 255) / 256, 256, 0, stream>>>(x, W1, dinvF, ts1F, N);
        k_scatter<<<(E * 16) / 256, 256, 0, stream>>>(row, col, ts1F, ts2F, E);
        k_finalize<<<(N * 16 + 255) / 256, 256, 0, stream>>>(ts2F, ts1F, dinvF, b1, N, 1);
        k_gemm2f<<<N / 16, 256, 0, stream>>>(ts2F, W2, dinvF, ts1F, N);
        hipMemsetAsync(ts2F, 0, (size_t)N * 64, stream);
        k_scatter<<<(E * 16) / 256, 256, 0, stream>>>(row, col, ts1F, ts2F, E);
        k_finalize<<<(N * 16 + 255) / 256, 256, 0, stream>>>(ts2F, ts1F, dinvF, b2, N, 0);
        k_scoref<<<(E + 255) / 256, 256, 0, stream>>>(row, col, ts2F, out, E);
    }
}

// Round 3
// 382.093 us; speedup vs baseline: 2.5955x; 2.5955x over previous
//
#include <hip/hip_runtime.h>
#include <hip/hip_bf16.h>
#include <hip/hip_fp16.h>
#include <math.h>

// GCN link prediction. R14: restore the R11 register-accumulating CSR gather
// (R13's LDS-atomic aggregation was 15x worse: 347us pAgg1, VALUBusy 0.8%),
// but fuse the in-bucket counting sort (old pC2) INTO the gather kernels:
// buckets shrink to 128 nodes (NBUK=782), each gather block stages+sorts its
// ~4096 edges in LDS (32KB), then does the proven 8-lane/node register gather
// from LDS. Deletes pC2 + ebuf2/start round-trip (~26MB). Degree atomics are
// folded into pA; dinv computed in k_gemm1 (both proven in R13's run).
//   deg[v] = incount(col==v)+1 ; dinv = rsqrt(deg)
//   ts[v]  = (h[v]@W)*dinv[v]          (fp16 gather tables, L2-resident)
//   h'[c]  = act(dinv[c]*(sum_{e:col=c} ts[row_e] + ts[c]) + b)
//   score  = sigmoid(dot(h2[row], h2[col]))

#define BSH 7
#define BSZ 128            // nodes per bucket -> NBUK = 782 (<= 1024)
#define CAP 8192           // max LDS-staged edges per bucket (avg 4096, +64 sigma)
#define MAXCH 3200         // edges per chunk (multiple of 4)
#define MAXCHUNKS 1024

// ---- Phase A: per-(chunk,bucket) histogram -> M[b][NBUK]; node degree atomics ----
__global__ __launch_bounds__(512) void pA(const int* __restrict__ col,
                                          int* __restrict__ M, int* __restrict__ degi,
                                          int E, int CH, int NBUK) {
    __shared__ int hist[1024];
    const int t = threadIdx.x, b = blockIdx.x;
    for (int i = t; i < 1024; i += 512) hist[i] = 0;
    __syncthreads();
    const int s = b * CH, e = min(E, s + CH);
    const int n4 = (e - s) >> 2;                 // CH % 4 == 0 -> 16B-aligned
    const int4* c4 = (const int4*)(col + s);
    for (int i = t; i < n4; i += 512) {
        int4 c = c4[i];
        atomicAdd(&hist[c.x >> BSH], 1); atomicAdd(&degi[c.x], 1);
        atomicAdd(&hist[c.y >> BSH], 1); atomicAdd(&degi[c.y], 1);
        atomicAdd(&hist[c.z >> BSH], 1); atomicAdd(&degi[c.z], 1);
        atomicAdd(&hist[c.w >> BSH], 1); atomicAdd(&degi[c.w], 1);
    }
    for (int i = s + (n4 << 2) + t; i < e; i += 512) {
        int c = col[i];
        atomicAdd(&hist[c >> BSH], 1);
        atomicAdd(&degi[c], 1);
    }
    __syncthreads();
    for (int i = t; i < NBUK; i += 512) M[b * NBUK + i] = hist[i];
}

// ---- Phase B1: per-bucket exclusive scan over CN chunks (CN <= 1024) ----
__global__ __launch_bounds__(1024) void pB1(int* __restrict__ M, int* __restrict__ T,
                                            int NBUK, int CN) {
    __shared__ int s[1024];
    const int t = threadIdx.x, k = blockIdx.x;
    int own = (t < CN) ? M[t * NBUK + k] : 0;
    s[t] = own;
    __syncthreads();
    for (int d = 1; d < 1024; d <<= 1) {
        int add = (t >= d) ? s[t - d] : 0;
        __syncthreads();
        s[t] += add;
        __syncthreads();
    }
    if (t < CN) M[t * NBUK + k] = s[t] - own;
    if (t == 1023) T[k] = s[1023];
}

// ---- Phase B2: exclusive scan of bucket totals -> S[0..NBUK] (NBUK <= 1024) ----
__global__ __launch_bounds__(1024) void pB2(const int* __restrict__ T, int* __restrict__ S,
                                            int NBUK) {
    __shared__ int s[1024];
    const int t = threadIdx.x;
    int own = (t < NBUK) ? T[t] : 0;
    s[t] = own;
    __syncthreads();
    for (int d = 1; d < 1024; d <<= 1) {
        int add = (t >= d) ? s[t - d] : 0;
        __syncthreads();
        s[t] += add;
        __syncthreads();
    }
    if (t < NBUK) S[t] = s[t] - own;
    if (t == 1023) S[NBUK] = s[1023];
}

// ---- Phase C: LDS-staged bucket placement -> coalesced run writes ----
__global__ __launch_bounds__(1024) void pC(const int* __restrict__ row, const int* __restrict__ col,
                                           const int* __restrict__ M, const int* __restrict__ S,
                                           unsigned int* __restrict__ ebuf, int E, int CH, int NBUK) {
    __shared__ unsigned int se[MAXCH];        // chunk edges, bucket-ordered
    __shared__ unsigned short pk[MAXCH];      // bucket id per LDS slot
    __shared__ int lhist[1024], lbase[1024], lcur[1024], gbase[1024];
    const int t = threadIdx.x, b = blockIdx.x;
    lhist[t] = 0;
    __syncthreads();
    const int s = b * CH, e = min(E, s + CH);
    const int cnt = e - s;
    const int n4 = cnt >> 2;
    const int4* c4 = (const int4*)(col + s);
    const int4* r4 = (const int4*)(row + s);
    for (int i = t; i < n4; i += 1024) {
        int4 c = c4[i];
        atomicAdd(&lhist[c.x >> BSH], 1);
        atomicAdd(&lhist[c.y >> BSH], 1);
        atomicAdd(&lhist[c.z >> BSH], 1);
        atomicAdd(&lhist[c.w >> BSH], 1);
    }
    for (int i = (n4 << 2) + t; i < cnt; i += 1024) atomicAdd(&lhist[col[s + i] >> BSH], 1);
    __syncthreads();
    {   // 1024-wide exclusive scan of lhist -> lbase (scratch in lcur)
        int own = lhist[t];
        lcur[t] = own;
        __syncthreads();
        for (int d = 1; d < 1024; d <<= 1) {
            int add = (t >= d) ? lcur[t - d] : 0;
            __syncthreads();
            lcur[t] += add;
            __syncthreads();
        }
        lbase[t] = lcur[t] - own;
        lcur[t] = lbase[t];
        __syncthreads();
        if (t < NBUK) gbase[t] = S[t] + M[b * NBUK + t] - lbase[t];
    }
    __syncthreads();
    // placement into LDS (bucket-ordered)
    for (int i = t; i < n4; i += 1024) {
        int4 c = c4[i];
        int4 r = r4[i];
        int k0 = c.x >> BSH, p0 = atomicAdd(&lcur[k0], 1);
        se[p0] = ((unsigned int)(c.x & (BSZ - 1)) << 17) | (unsigned int)r.x; pk[p0] = (unsigned short)k0;
        int k1 = c.y >> BSH, p1 = atomicAdd(&lcur[k1], 1);
        se[p1] = ((unsigned int)(c.y & (BSZ - 1)) << 17) | (unsigned int)r.y; pk[p1] = (unsigned short)k1;
        int k2 = c.z >> BSH, p2 = atomicAdd(&lcur[k2], 1);
        se[p2] = ((unsigned int)(c.z & (BSZ - 1)) << 17) | (unsigned int)r.z; pk[p2] = (unsigned short)k2;
        int k3 = c.w >> BSH, p3 = atomicAdd(&lcur[k3], 1);
        se[p3] = ((unsigned int)(c.w & (BSZ - 1)) << 17) | (unsigned int)r.w; pk[p3] = (unsigned short)k3;
    }
    for (int i = (n4 << 2) + t; i < cnt; i += 1024) {
        int c = col[s + i], r = row[s + i];
        int k = c >> BSH, p = atomicAdd(&lcur[k], 1);
        se[p] = ((unsigned int)(c & (BSZ - 1)) << 17) | (unsigned int)r; pk[p] = (unsigned short)k;
    }
    __syncthreads();
    // coalesced write-out: consecutive LDS slots in a bucket -> consecutive global
    for (int i = t; i < cnt; i += 1024) {
        int k = pk[i];
        ebuf[gbase[k] + i] = se[i];
    }
}

// ---- GEMM1: dinv[v] = rsqrt(deg+1); ts1h[v] = half((x[v] @ W1) * dinv[v]) ----
__global__ __launch_bounds__(256) void k_gemm1(
    const float* __restrict__ x, const float* __restrict__ W1,
    const int* __restrict__ degi, float* __restrict__ dinv,
    __half* __restrict__ ts, int N) {
    __shared__ float wsT[16 * 132];
    const int tid = threadIdx.x;
    for (int idx = tid; idx < 2048; idx += 256) {
        int k = idx >> 4, c = idx & 15;
        wsT[c * 132 + k] = W1[idx];
    }
    __syncthreads();
    const int n = blockIdx.x * 256 + tid;
    if (n >= N) return;
    const float4* xr = (const float4*)(x + (size_t)n * 128);
    float acc[16];
    #pragma unroll
    for (int c = 0; c < 16; ++c) acc[c] = 0.f;
    #pragma unroll 4
    for (int k4 = 0; k4 < 32; ++k4) {
        float4 a = xr[k4];
        #pragma unroll
        for (int c = 0; c < 16; ++c) {
            const float4 w = *(const float4*)&wsT[c * 132 + k4 * 4];
            acc[c] = fmaf(a.x, w.x, fmaf(a.y, w.y, fmaf(a.z, w.z, fmaf(a.w, w.w, acc[c]))));
        }
    }
    const float dv = rsqrtf((float)degi[n] + 1.0f);
    dinv[n] = dv;
    union { __half h[16]; uint4 u[2]; } o;
    #pragma unroll
    for (int c = 0; c < 16; ++c) o.h[c] = __float2half(acc[c] * dv);
    uint4* dst = (uint4*)(ts + (size_t)n * 16);
    dst[0] = o.u[0]; dst[1] = o.u[1];
}

// ---- Layer-1 aggregation: per-bucket LDS stage + counting sort, then
//      8-lane/node register gather; fused bias/ReLU + 16x16 W2 epilogue ----
__global__ __launch_bounds__(512) void pG1(
    const unsigned int* __restrict__ ebuf, const int* __restrict__ S,
    const __half2* __restrict__ tsv, const float* __restrict__ dinv,
    const float* __restrict__ b1, const float* __restrict__ W2,
    __half2* __restrict__ ts2v, int N) {
    __shared__ unsigned int se[CAP];
    __shared__ int h[BSZ], sc[BSZ], cur[BSZ];
    __shared__ float w2s[256];
    const int t = threadIdx.x, k = blockIdx.x;
    if (t < BSZ) h[t] = 0;
    if (t < 256) w2s[t] = W2[t];
    __syncthreads();
    const int s = S[k], e = S[k + 1];
    const int cnt = e - s;
    if (cnt <= CAP) {
        for (int i = s + t; i < e; i += 512) atomicAdd(&h[ebuf[i] >> 17], 1);
        __syncthreads();
        if (t < BSZ) sc[t] = h[t];
        __syncthreads();
        for (int d = 1; d < BSZ; d <<= 1) {
            int add = (t < BSZ && t >= d) ? sc[t - d] : 0;
            __syncthreads();
            if (t < BSZ) sc[t] += add;
            __syncthreads();
        }
        if (t < BSZ) cur[t] = sc[t] - h[t];
        __syncthreads();
        for (int i = s + t; i < e; i += 512) {        // second read: L1/L2 hit
            unsigned int w = ebuf[i];
            int p = atomicAdd(&cur[w >> 17], 1);
            se[p] = w;
        }
        __syncthreads();
    }
    const int l = t & 7;                 // channel pair: c0=2l, c1=2l+1
    #pragma unroll
    for (int sweep = 0; sweep < 2; ++sweep) {
        const int lv = (t >> 3) + (sweep << 6);
        const int v = (k << BSH) + lv;
        if (v >= N) continue;
        float sx = 0.f, sy = 0.f;
        if (cnt <= CAP) {
            const int pe = sc[lv];
            int i = pe - h[lv];
            for (; i + 4 <= pe; i += 4) {
                unsigned int w0 = se[i], w1 = se[i + 1], w2 = se[i + 2], w3 = se[i + 3];
                float2 f0 = __half22float2(tsv[(size_t)(w0 & 0x1FFFF) * 8 + l]);
                float2 f1 = __half22float2(tsv[(size_t)(w1 & 0x1FFFF) * 8 + l]);
                float2 f2 = __half22float2(tsv[(size_t)(w2 & 0x1FFFF) * 8 + l]);
                float2 f3 = __half22float2(tsv[(size_t)(w3 & 0x1FFFF) * 8 + l]);
                sx += (f0.x + f1.x) + (f2.x + f3.x);
                sy += (f0.y + f1.y) + (f2.y + f3.y);
            }
            for (; i < pe; ++i) {
                unsigned int w = se[i];
                float2 f = __half22float2(tsv[(size_t)(w & 0x1FFFF) * 8 + l]);
                sx += f.x; sy += f.y;
            }
        } else {
            // overflow fallback (never taken for benchmark distribution): match-scan
            for (int j = s; j < e; ++j) {
                unsigned int w = ebuf[j];
                if ((int)(w >> 17) == lv) {
                    float2 f = __half22float2(tsv[(size_t)(w & 0x1FFFF) * 8 + l]);
                    sx += f.x; sy += f.y;
                }
            }
        }
        const float dv = dinv[v];
        float2 sf = __half22float2(tsv[(size_t)v * 8 + l]);
        float hx = fmaxf(dv * (sx + sf.x) + b1[2 * l],     0.f);
        float hy = fmaxf(dv * (sy + sf.y) + b1[2 * l + 1], 0.f);
        float ox = 0.f, oy = 0.f;
        #pragma unroll
        for (int j = 0; j < 8; ++j) {
            float ax = __shfl(hx, j, 8);       // channel 2j
            float ay = __shfl(hy, j, 8);       // channel 2j+1
            ox = fmaf(ax, w2s[(2 * j) * 16 + 2 * l],     fmaf(ay, w2s[(2 * j + 1) * 16 + 2 * l],     ox));
            oy = fmaf(ax, w2s[(2 * j) * 16 + 2 * l + 1], fmaf(ay, w2s[(2 * j + 1) * 16 + 2 * l + 1], oy));
        }
        ts2v[(size_t)v * 8 + l] = __halves2half2(__float2half(dv * ox), __float2half(dv * oy));
    }
}

// ---- Layer-2 aggregation: same stage+sort+gather; epilogue bias only ----
__global__ __launch_bounds__(512) void pG2(
    const unsigned int* __restrict__ ebuf, const int* __restrict__ S,
    const __half2* __restrict__ tsv, const float* __restrict__ dinv,
    const float* __restrict__ b2, __half2* __restrict__ h2v, int N) {
    __shared__ unsigned int se[CAP];
    __shared__ int h[BSZ], sc[BSZ], cur[BSZ];
    const int t = threadIdx.x, k = blockIdx.x;
    if (t < BSZ) h[t] = 0;
    __syncthreads();
    const int s = S[k], e = S[k + 1];
    const int cnt = e - s;
    if (cnt <= CAP) {
        for (int i = s + t; i < e; i += 512) atomicAdd(&h[ebuf[i] >> 17], 1);
        __syncthreads();
        if (t < BSZ) sc[t] = h[t];
        __syncthreads();
        for (int d = 1; d < BSZ; d <<= 1) {
            int add = (t < BSZ && t >= d) ? sc[t - d] : 0;
            __syncthreads();
            if (t < BSZ) sc[t] += add;
            __syncthreads();
        }
        if (t < BSZ) cur[t] = sc[t] - h[t];
        __syncthreads();
        for (int i = s + t; i < e; i += 512) {
            unsigned int w = ebuf[i];
            int p = atomicAdd(&cur[w >> 17], 1);
            se[p] = w;
        }
        __syncthreads();
    }
    const int l = t & 7;
    #pragma unroll
    for (int sweep = 0; sweep < 2; ++sweep) {
        const int lv = (t >> 3) + (sweep << 6);
        const int v = (k << BSH) + lv;
        if (v >= N) continue;
        float sx = 0.f, sy = 0.f;
        if (cnt <= CAP) {
            const int pe = sc[lv];
            int i = pe - h[lv];
            for (; i + 4 <= pe; i += 4) {
                unsigned int w0 = se[i], w1 = se[i + 1], w2 = se[i + 2], w3 = se[i + 3];
                float2 f0 = __half22float2(tsv[(size_t)(w0 & 0x1FFFF) * 8 + l]);
                float2 f1 = __half22float2(tsv[(size_t)(w1 & 0x1FFFF) * 8 + l]);
                float2 f2 = __half22float2(tsv[(size_t)(w2 & 0x1FFFF) * 8 + l]);
                float2 f3 = __half22float2(tsv[(size_t)(w3 & 0x1FFFF) * 8 + l]);
                sx += (f0.x + f1.x) + (f2.x + f3.x);
                sy += (f0.y + f1.y) + (f2.y + f3.y);
            }
            for (; i < pe; ++i) {
                unsigned int w = se[i];
                float2 f = __half22float2(tsv[(size_t)(w & 0x1FFFF) * 8 + l]);
                sx += f.x; sy += f.y;
            }
        } else {
            for (int j = s; j < e; ++j) {
                unsigned int w = ebuf[j];
                if ((int)(w >> 17) == lv) {
                    float2 f = __half22float2(tsv[(size_t)(w & 0x1FFFF) * 8 + l]);
                    sx += f.x; sy += f.y;
                }
            }
        }
        float2 sf = __half22float2(tsv[(size_t)v * 8 + l]);
        const float dv = dinv[v];
        h2v[(size_t)v * 8 + l] = __halves2half2(
            __float2half(dv * (sx + sf.x) + b2[2 * l]),
            __float2half(dv * (sy + sf.y) + b2[2 * l + 1]));
    }
}

// ---- Edge scores (R8/R10-proven: 1 edge/thread, no NT) ----
__global__ void k_score(const int* __restrict__ row, const int* __restrict__ col,
                        const __half* __restrict__ h2h, float* __restrict__ out, int E) {
    int e = blockIdx.x * 256 + threadIdx.x;
    if (e < E) {
        union { uint4 u[2]; __half2 h[8]; } a, b;
        const uint4* pa = (const uint4*)(h2h + (size_t)row[e] * 16);
        const uint4* pb = (const uint4*)(h2h + (size_t)col[e] * 16);
        a.u[0] = pa[0]; a.u[1] = pa[1];
        b.u[0] = pb[0]; b.u[1] = pb[1];
        float d = 0.f;
        #pragma unroll
        for (int i = 0; i < 8; ++i) {
            float2 fa = __half22float2(a.h[i]);
            float2 fb = __half22float2(b.h[i]);
            d = fmaf(fa.x, fb.x, fmaf(fa.y, fb.y, d));
        }
        out[e] = 1.0f / (1.0f + __expf(-d));
    }
}

// ---------------- Fallback (R2 atomic path) ----------------
__global__ void k_countf(const int* __restrict__ col, float* __restrict__ deg, int E) {
    int e = blockIdx.x * 256 + threadIdx.x;
    if (e < E) atomicAdd(&deg[col[e]], 1.0f);
}
__global__ void k_dinvf(float* __restrict__ dinv, int N) {
    int v = blockIdx.x * 256 + threadIdx.x;
    if (v < N) dinv[v] = rsqrtf(dinv[v] + 1.0f);
}
__global__ __launch_bounds__(256) void k_gemm1f(
    const float* __restrict__ x, const float* __restrict__ W1,
    const float* __restrict__ dinv, float* __restrict__ ts, int N) {
    __shared__ float wsT[16 * 132];
    const int tid = threadIdx.x;
    for (int idx = tid; idx < 2048; idx += 256) {
        int k = idx >> 4, c = idx & 15;
        wsT[c * 132 + k] = W1[idx];
    }
    __syncthreads();
    const int n = blockIdx.x * 256 + tid;
    if (n >= N) return;
    const float4* xr = (const float4*)(x + (size_t)n * 128);
    float acc[16];
    #pragma unroll
    for (int c = 0; c < 16; ++c) acc[c] = 0.f;
    for (int k4 = 0; k4 < 32; ++k4) {
        float4 a = xr[k4];
        #pragma unroll
        for (int c = 0; c < 16; ++c) {
            const float4 w = *(const float4*)&wsT[c * 132 + k4 * 4];
            acc[c] = fmaf(a.x, w.x, fmaf(a.y, w.y, fmaf(a.z, w.z, fmaf(a.w, w.w, acc[c]))));
        }
    }
    float dv = dinv[n];
    float4* o = (float4*)(ts + (size_t)n * 16);
    #pragma unroll
    for (int q = 0; q < 4; ++q)
        o[q] = make_float4(acc[4*q] * dv, acc[4*q+1] * dv, acc[4*q+2] * dv, acc[4*q+3] * dv);
}
__global__ void k_scatter(const int* __restrict__ row, const int* __restrict__ col,
                          const float* __restrict__ ts, float* __restrict__ acc, int E) {
    int g = blockIdx.x * 256 + threadIdx.x;
    int e = g >> 4, c = g & 15;
    if (e < E) atomicAdd(&acc[(size_t)col[e] * 16 + c], ts[(size_t)row[e] * 16 + c]);
}
__global__ void k_finalize(float* __restrict__ acc, const float* __restrict__ ts,
                           const float* __restrict__ dinv, const float* __restrict__ b,
                           int N, int relu) {
    int g = blockIdx.x * 256 + threadIdx.x;
    int v = g >> 4, c = g & 15;
    if (v < N) {
        float h = dinv[v] * (acc[g] + ts[g]) + b[c];
        if (relu) h = fmaxf(h, 0.f);
        acc[g] = h;
    }
}
__global__ __launch_bounds__(256) void k_gemm2f(
    const float* __restrict__ h1, const float* __restrict__ W2,
    const float* __restrict__ dinv, float* __restrict__ ts2, int N) {
    __shared__ float hs[16 * 17];
    __shared__ float ws2[256];
    const int tid = threadIdx.x;
    const int base = blockIdx.x * 16;
    if (tid < 64) ((float4*)ws2)[tid] = ((const float4*)W2)[tid];
    if (tid >= 64 && tid < 128) {
        int t2 = tid - 64;
        float4 v4 = ((const float4*)(h1 + (size_t)base * 16))[t2];
        float* d = &hs[(t2 >> 2) * 17 + (t2 & 3) * 4];
        d[0] = v4.x; d[1] = v4.y; d[2] = v4.z; d[3] = v4.w;
    }
    __syncthreads();
    const int r = tid >> 4, c = tid & 15;
    float a = 0.f;
    #pragma unroll
    for (int kk = 0; kk < 16; ++kk) a = fmaf(hs[r * 17 + kk], ws2[kk * 16 + c], a);
    ts2[(size_t)(base + r) * 16 + c] = a * dinv[base + r];
}
__global__ void k_scoref(const int* __restrict__ row, const int* __restrict__ col,
                         const float* __restrict__ h2, float* __restrict__ out, int E) {
    int e = blockIdx.x * 256 + threadIdx.x;
    if (e < E) {
        const float4* a = (const float4*)(h2 + (size_t)row[e] * 16);
        const float4* b = (const float4*)(h2 + (size_t)col[e] * 16);
        float d = 0.f;
        #pragma unroll
        for (int i = 0; i < 4; ++i) {
            float4 u = a[i], v = b[i];
            d += u.x * v.x + u.y * v.y + u.z * v.z + u.w * v.w;
        }
        out[e] = 1.0f / (1.0f + __expf(-d));
    }
}

extern "C" void kernel_launch(void* const* d_in, const int* in_sizes, int n_in,
                              void* d_out, int out_size, void* d_ws, size_t ws_size,
                              hipStream_t stream) {
    const float* x  = (const float*)d_in[0];
    const int*   ei = (const int*)d_in[1];
    const float* W1 = (const float*)d_in[2];
    const float* b1 = (const float*)d_in[3];
    const float* W2 = (const float*)d_in[4];
    const float* b2 = (const float*)d_in[5];

    const int N = in_sizes[0] / 128;   // 100000
    const int E = in_sizes[1] / 2;     // 3200000
    const int* row = ei;
    const int* col = ei + E;
    float* out = (float*)d_out;

    const int NBUK = (N + BSZ - 1) / BSZ;          // 782
    const int CN = (E + MAXCH - 1) / MAXCH;        // 1000 chunks
    const int CH = MAXCH;                          // 3200, multiple of 4

    char* ws = (char*)d_ws;
    size_t off = 0;
    auto alloc = [&](size_t bytes) { void* p = ws + off; off += (bytes + 255) & ~(size_t)255; return p; };
    float*  dinv  = (float*)alloc((size_t)N * 4);
    __half* ts1h  = (__half*)alloc((size_t)N * 32);    // also h2h after pG1
    __half* ts2h  = (__half*)alloc((size_t)N * 32);
    int*    degi  = (int*)alloc((size_t)N * 4);
    int*    M     = (int*)alloc((size_t)CN * NBUK * 4);
    int*    T     = (int*)alloc((size_t)NBUK * 4);
    int*    S     = (int*)alloc((size_t)(NBUK + 1) * 4);
    unsigned int* ebuf  = (unsigned int*)alloc((size_t)E * 4);
    const size_t need = off;    // ~24 MB at N=100k, E=3.2M

    if (N <= 131072 && NBUK <= 1024 && CN <= MAXCHUNKS && ws_size >= need) {
        hipMemsetAsync(degi, 0, (size_t)N * 4, stream);
        pA <<<CN, 512, 0, stream>>>(col, M, degi, E, CH, NBUK);
        pB1<<<NBUK, 1024, 0, stream>>>(M, T, NBUK, CN);
        pB2<<<1, 1024, 0, stream>>>(T, S, NBUK);
        k_gemm1<<<(N + 255) / 256, 256, 0, stream>>>(x, W1, degi, dinv, ts1h, N);
        pC <<<CN, 1024, 0, stream>>>(row, col, M, S, ebuf, E, CH, NBUK);
        pG1<<<NBUK, 512, 0, stream>>>(ebuf, S, (const __half2*)ts1h, dinv, b1, W2,
                                      (__half2*)ts2h, N);
        __half* h2h = ts1h;   // ts1h dead after pG1
        pG2<<<NBUK, 512, 0, stream>>>(ebuf, S, (const __half2*)ts2h, dinv, b2,
                                      (__half2*)h2h, N);
        k_score<<<(E + 255) / 256, 256, 0, stream>>>(row, col, h2h, out, E);
    } else {
        // R2 fallback, fp32 buffers carved independently
        float* dinvF = (float*)ws;
        float* ts1F  = (float*)(ws + (size_t)N * 4);
        float* ts2F  = (float*)(ws + (size_t)N * 4 + (size_t)N * 64);
        hipMemsetAsync(dinvF, 0, (size_t)N * 4, stream);
        hipMemsetAsync(ts2F, 0, (size_t)N * 64, stream);
        k_countf<<<(E + 255) / 256, 256, 0, stream>>>(col, dinvF, E);
        k_dinvf<<<(N + 255) / 256, 256, 0, stream>>>(dinvF, N);
        k_gemm1f<<<(N + 255) / 256, 256, 0, stream>>>(x, W1, dinvF, ts1F, N);
        k_scatter<<<(E * 16) / 256, 256, 0, stream>>>(row, col, ts1F, ts2F, E);
        k_finalize<<<(N * 16 + 255) / 256, 256, 0, stream>>>(ts2F, ts1F, dinvF, b1, N, 1);
        k_gemm2f<<<N / 16, 256, 0, stream>>>(ts2F, W2, dinvF, ts1F, N);
        hipMemsetAsync(ts2F, 0, (size_t)N * 64, stream);
        k_scatter<<<(E * 16) / 256, 256, 0, stream>>>(row, col, ts1F, ts2F, E);
        k_finalize<<<(N * 16 + 255) / 256, 256, 0, stream>>>(ts2F, ts1F, dinvF, b2, N, 0);
        k_scoref<<<(E + 255) / 256, 256, 0, stream>>>(row, col, ts2F, out, E);
    }
}

// Round 5
// 257.628 us; speedup vs baseline: 3.8494x; 1.4831x over previous
//
#include <hip/hip_runtime.h>
#include <hip/hip_bf16.h>
#include <hip/hip_fp16.h>
#include <math.h>

// GCN link prediction. R16 = R15 resubmitted unchanged (R15 bench was an
// infra failure: "MI355X container failed twice", no counters). Structure:
// R11 (proven 253.9us) with the front-end scan pipeline (pA+pB1+pB2) deleted:
// fixed-capacity buckets (CAPB=32768 = 2x avg fill) let pSort grab each
// chunk's per-bucket write base with ONE atomicAdd per (block,bucket) on
// gcur[196] instead of the 3-kernel histogram+scan. Bucket k occupies
// ebuf[k*CAPB .. k*CAPB+gcur[k]). Degree comes free from pS2's in-bucket
// histogram (R14 showed per-edge global degree atomics cost ~90us). In-bucket
// edge order is atomic-arrival nondeterministic: fp32 reorder jitter ~1e-7
// << fp16 absmax 0.0039.
//   deg[v] = incount(col==v)+1 ; dinv = rsqrt(deg)
//   ts[v]  = (h[v]@W)*dinv[v]          (fp16 gather tables, L2-resident)
//   h'[c]  = act(dinv[c]*(sum_{e:col=c} ts[row_e] + ts[c]) + b)
//   score  = sigmoid(dot(h2[row], h2[col]))

#define BSH 9
#define BSZ 512            // nodes per bucket -> NBUK = 196 (<= 256)
#define CAPB 32768         // slots per bucket (2x avg 16327; +128 sigma)
#define MAXCH 3200         // edges per chunk (multiple of 4)
#define MAXCHUNKS 1024

// ---- pSort: chunk histogram -> atomic base grab -> LDS bucket-order ->
//      coalesced run writes into fixed-capacity bucket regions ----
__global__ __launch_bounds__(512) void pSort(
    const int* __restrict__ row, const int* __restrict__ col,
    int* __restrict__ gcur, unsigned int* __restrict__ ebuf,
    int E, int CH, int NBUK) {
    __shared__ unsigned int se[MAXCH];        // chunk edges, bucket-ordered
    __shared__ unsigned short pk[MAXCH];      // bucket id per LDS slot
    __shared__ int lhist[256], lbase[256], lcur[256], gbase[256];
    const int t = threadIdx.x, b = blockIdx.x;
    if (t < 256) lhist[t] = 0;
    __syncthreads();
    const int s = b * CH, e = min(E, s + CH);
    const int cnt = e - s;
    const int n4 = cnt >> 2;
    const int4* c4 = (const int4*)(col + s);
    const int4* r4 = (const int4*)(row + s);
    for (int i = t; i < n4; i += 512) {
        int4 c = c4[i];
        atomicAdd(&lhist[c.x >> BSH], 1);
        atomicAdd(&lhist[c.y >> BSH], 1);
        atomicAdd(&lhist[c.z >> BSH], 1);
        atomicAdd(&lhist[c.w >> BSH], 1);
    }
    for (int i = (n4 << 2) + t; i < cnt; i += 512) atomicAdd(&lhist[col[s + i] >> BSH], 1);
    __syncthreads();
    {   // 256-wide exclusive scan of lhist -> lbase (scratch in lcur); threads 0-255
        int own = (t < 256) ? lhist[t] : 0;
        if (t < 256) lcur[t] = own;
        __syncthreads();
        for (int d = 1; d < 256; d <<= 1) {
            int add = (t < 256 && t >= d) ? lcur[t - d] : 0;
            __syncthreads();
            if (t < 256) lcur[t] += add;
            __syncthreads();
        }
        if (t < 256) {
            lbase[t] = lcur[t] - own;
            lcur[t] = lcur[t] - own;
        }
        __syncthreads();
        if (t < NBUK) {   // grab this chunk's range in bucket t
            int base = atomicAdd(&gcur[t], lhist[t]);
            gbase[t] = t * CAPB + base - lbase[t];
        }
    }
    __syncthreads();
    // placement into LDS (bucket-ordered)
    for (int i = t; i < n4; i += 512) {
        int4 c = c4[i];
        int4 r = r4[i];
        int k0 = c.x >> BSH, p0 = atomicAdd(&lcur[k0], 1);
        se[p0] = ((unsigned int)(c.x & (BSZ - 1)) << 17) | (unsigned int)r.x; pk[p0] = (unsigned short)k0;
        int k1 = c.y >> BSH, p1 = atomicAdd(&lcur[k1], 1);
        se[p1] = ((unsigned int)(c.y & (BSZ - 1)) << 17) | (unsigned int)r.y; pk[p1] = (unsigned short)k1;
        int k2 = c.z >> BSH, p2 = atomicAdd(&lcur[k2], 1);
        se[p2] = ((unsigned int)(c.z & (BSZ - 1)) << 17) | (unsigned int)r.z; pk[p2] = (unsigned short)k2;
        int k3 = c.w >> BSH, p3 = atomicAdd(&lcur[k3], 1);
        se[p3] = ((unsigned int)(c.w & (BSZ - 1)) << 17) | (unsigned int)r.w; pk[p3] = (unsigned short)k3;
    }
    for (int i = (n4 << 2) + t; i < cnt; i += 512) {
        int c = col[s + i], r = row[s + i];
        int k = c >> BSH, p = atomicAdd(&lcur[k], 1);
        se[p] = ((unsigned int)(c & (BSZ - 1)) << 17) | (unsigned int)r; pk[p] = (unsigned short)k;
    }
    __syncthreads();
    // coalesced write-out: consecutive LDS slots in a bucket -> consecutive global
    for (int i = t; i < cnt; i += 512) {
        int k = pk[i];
        ebuf[gbase[k] + i] = se[i];
    }
}

// ---- pS2: in-bucket counting sort by local col; emits dinv and CSR start ----
__global__ __launch_bounds__(1024) void pS2(const unsigned int* __restrict__ ebuf,
                                            const int* __restrict__ gcur,
                                            unsigned int* __restrict__ ebuf2,
                                            float* __restrict__ dinv,
                                            int* __restrict__ start, int N) {
    __shared__ int h[BSZ], sc[BSZ], cur[BSZ];
    const int t = threadIdx.x, k = blockIdx.x;
    if (t < BSZ) h[t] = 0;
    __syncthreads();
    const int s = k * CAPB, e = s + gcur[k];
    for (int i = s + t; i < e; i += 1024) atomicAdd(&h[ebuf[i] >> 17], 1);
    __syncthreads();
    if (t < BSZ) sc[t] = h[t];
    __syncthreads();
    for (int d = 1; d < BSZ; d <<= 1) {
        int add = (t < BSZ && t >= d) ? sc[t - d] : 0;
        __syncthreads();
        if (t < BSZ) sc[t] += add;
        __syncthreads();
    }
    if (t < BSZ) {
        cur[t] = sc[t] - h[t];             // exclusive scan
        const int v = (k << BSH) + t;
        if (v < N) {
            dinv[v] = rsqrtf((float)h[t] + 1.0f);
            start[v] = s + cur[t];
        }
    }
    __syncthreads();
    for (int i = s + t; i < e; i += 1024) {
        unsigned int w = ebuf[i];
        int p = atomicAdd(&cur[w >> 17], 1);
        ebuf2[s + p] = w;
    }
}

// ---- GEMM1: ts1h[v] = half((x[v] @ W1) * dinv[v]) ----
__global__ __launch_bounds__(256) void k_gemm1(
    const float* __restrict__ x, const float* __restrict__ W1,
    const float* __restrict__ dinv, __half* __restrict__ ts, int N) {
    __shared__ float wsT[16 * 132];
    const int tid = threadIdx.x;
    for (int idx = tid; idx < 2048; idx += 256) {
        int k = idx >> 4, c = idx & 15;
        wsT[c * 132 + k] = W1[idx];
    }
    __syncthreads();
    const int n = blockIdx.x * 256 + tid;
    if (n >= N) return;
    const float4* xr = (const float4*)(x + (size_t)n * 128);
    float acc[16];
    #pragma unroll
    for (int c = 0; c < 16; ++c) acc[c] = 0.f;
    #pragma unroll 4
    for (int k4 = 0; k4 < 32; ++k4) {
        float4 a = xr[k4];
        #pragma unroll
        for (int c = 0; c < 16; ++c) {
            const float4 w = *(const float4*)&wsT[c * 132 + k4 * 4];
            acc[c] = fmaf(a.x, w.x, fmaf(a.y, w.y, fmaf(a.z, w.z, fmaf(a.w, w.w, acc[c]))));
        }
    }
    float dv = dinv[n];
    union { __half h[16]; uint4 u[2]; } o;
    #pragma unroll
    for (int c = 0; c < 16; ++c) o.h[c] = __float2half(acc[c] * dv);
    uint4* dst = (uint4*)(ts + (size_t)n * 16);
    dst[0] = o.u[0]; dst[1] = o.u[1];
}

// ---- Layer-1 aggregation: 8 lanes/node, 8-deep unrolled CSR gather (no NT),
//      fused bias/ReLU + 16x16 W2 via width-8 shuffles (R11-proven) ----
__global__ __launch_bounds__(256) void pGat1(
    const unsigned int* __restrict__ ebuf2, const int* __restrict__ start,
    const int* __restrict__ gcur,
    const __half2* __restrict__ tsv, const float* __restrict__ dinv,
    const float* __restrict__ b1, const float* __restrict__ W2,
    __half2* __restrict__ ts2v, int N) {
    __shared__ float w2s[256];
    const int tid = threadIdx.x;
    w2s[tid] = W2[tid];
    __syncthreads();
    const int l = tid & 7;                 // channel pair: c0=2l, c1=2l+1
    const int v = blockIdx.x * 32 + (tid >> 3);
    if (v >= N) return;
    const int s = start[v];
    const int k = v >> BSH;
    const bool lastv = (((v + 1) & (BSZ - 1)) == 0) || (v + 1 >= N);
    const int e = lastv ? (k * CAPB + gcur[k]) : start[v + 1];
    float sx = 0.f, sy = 0.f;
    int i = s;
    for (; i + 8 <= e; i += 8) {
        unsigned int w0 = ebuf2[i],     w1 = ebuf2[i + 1];
        unsigned int w2 = ebuf2[i + 2], w3 = ebuf2[i + 3];
        unsigned int w4 = ebuf2[i + 4], w5 = ebuf2[i + 5];
        unsigned int w6 = ebuf2[i + 6], w7 = ebuf2[i + 7];
        float2 f0 = __half22float2(tsv[(size_t)(w0 & 0x1FFFF) * 8 + l]);
        float2 f1 = __half22float2(tsv[(size_t)(w1 & 0x1FFFF) * 8 + l]);
        float2 f2 = __half22float2(tsv[(size_t)(w2 & 0x1FFFF) * 8 + l]);
        float2 f3 = __half22float2(tsv[(size_t)(w3 & 0x1FFFF) * 8 + l]);
        float2 f4 = __half22float2(tsv[(size_t)(w4 & 0x1FFFF) * 8 + l]);
        float2 f5 = __half22float2(tsv[(size_t)(w5 & 0x1FFFF) * 8 + l]);
        float2 f6 = __half22float2(tsv[(size_t)(w6 & 0x1FFFF) * 8 + l]);
        float2 f7 = __half22float2(tsv[(size_t)(w7 & 0x1FFFF) * 8 + l]);
        sx += ((f0.x + f1.x) + (f2.x + f3.x)) + ((f4.x + f5.x) + (f6.x + f7.x));
        sy += ((f0.y + f1.y) + (f2.y + f3.y)) + ((f4.y + f5.y) + (f6.y + f7.y));
    }
    for (; i + 4 <= e; i += 4) {
        unsigned int w0 = ebuf2[i],     w1 = ebuf2[i + 1];
        unsigned int w2 = ebuf2[i + 2], w3 = ebuf2[i + 3];
        float2 f0 = __half22float2(tsv[(size_t)(w0 & 0x1FFFF) * 8 + l]);
        float2 f1 = __half22float2(tsv[(size_t)(w1 & 0x1FFFF) * 8 + l]);
        float2 f2 = __half22float2(tsv[(size_t)(w2 & 0x1FFFF) * 8 + l]);
        float2 f3 = __half22float2(tsv[(size_t)(w3 & 0x1FFFF) * 8 + l]);
        sx += (f0.x + f1.x) + (f2.x + f3.x);
        sy += (f0.y + f1.y) + (f2.y + f3.y);
    }
    for (; i < e; ++i) {
        unsigned int w = ebuf2[i];
        float2 f = __half22float2(tsv[(size_t)(w & 0x1FFFF) * 8 + l]);
        sx += f.x; sy += f.y;
    }
    const float dv = dinv[v];
    float2 sf = __half22float2(tsv[(size_t)v * 8 + l]);
    float hx = fmaxf(dv * (sx + sf.x) + b1[2 * l],     0.f);
    float hy = fmaxf(dv * (sy + sf.y) + b1[2 * l + 1], 0.f);
    float ox = 0.f, oy = 0.f;
    #pragma unroll
    for (int j = 0; j < 8; ++j) {
        float ax = __shfl(hx, j, 8);       // channel 2j
        float ay = __shfl(hy, j, 8);       // channel 2j+1
        ox = fmaf(ax, w2s[(2 * j) * 16 + 2 * l],     fmaf(ay, w2s[(2 * j + 1) * 16 + 2 * l],     ox));
        oy = fmaf(ax, w2s[(2 * j) * 16 + 2 * l + 1], fmaf(ay, w2s[(2 * j + 1) * 16 + 2 * l + 1], oy));
    }
    ts2v[(size_t)v * 8 + l] = __halves2half2(__float2half(dv * ox), __float2half(dv * oy));
}

// ---- Layer-2 aggregation: 8 lanes/node, 8-deep unrolled CSR gather + bias ----
__global__ __launch_bounds__(256) void pGat2(
    const unsigned int* __restrict__ ebuf2, const int* __restrict__ start,
    const int* __restrict__ gcur,
    const __half2* __restrict__ tsv, const float* __restrict__ dinv,
    const float* __restrict__ b2, __half2* __restrict__ h2v, int N) {
    const int tid = threadIdx.x;
    const int l = tid & 7;
    const int v = blockIdx.x * 32 + (tid >> 3);
    if (v >= N) return;
    const int s = start[v];
    const int k = v >> BSH;
    const bool lastv = (((v + 1) & (BSZ - 1)) == 0) || (v + 1 >= N);
    const int e = lastv ? (k * CAPB + gcur[k]) : start[v + 1];
    float sx = 0.f, sy = 0.f;
    int i = s;
    for (; i + 8 <= e; i += 8) {
        unsigned int w0 = ebuf2[i],     w1 = ebuf2[i + 1];
        unsigned int w2 = ebuf2[i + 2], w3 = ebuf2[i + 3];
        unsigned int w4 = ebuf2[i + 4], w5 = ebuf2[i + 5];
        unsigned int w6 = ebuf2[i + 6], w7 = ebuf2[i + 7];
        float2 f0 = __half22float2(tsv[(size_t)(w0 & 0x1FFFF) * 8 + l]);
        float2 f1 = __half22float2(tsv[(size_t)(w1 & 0x1FFFF) * 8 + l]);
        float2 f2 = __half22float2(tsv[(size_t)(w2 & 0x1FFFF) * 8 + l]);
        float2 f3 = __half22float2(tsv[(size_t)(w3 & 0x1FFFF) * 8 + l]);
        float2 f4 = __half22float2(tsv[(size_t)(w4 & 0x1FFFF) * 8 + l]);
        float2 f5 = __half22float2(tsv[(size_t)(w5 & 0x1FFFF) * 8 + l]);
        float2 f6 = __half22float2(tsv[(size_t)(w6 & 0x1FFFF) * 8 + l]);
        float2 f7 = __half22float2(tsv[(size_t)(w7 & 0x1FFFF) * 8 + l]);
        sx += ((f0.x + f1.x) + (f2.x + f3.x)) + ((f4.x + f5.x) + (f6.x + f7.x));
        sy += ((f0.y + f1.y) + (f2.y + f3.y)) + ((f4.y + f5.y) + (f6.y + f7.y));
    }
    for (; i + 4 <= e; i += 4) {
        unsigned int w0 = ebuf2[i],     w1 = ebuf2[i + 1];
        unsigned int w2 = ebuf2[i + 2], w3 = ebuf2[i + 3];
        float2 f0 = __half22float2(tsv[(size_t)(w0 & 0x1FFFF) * 8 + l]);
        float2 f1 = __half22float2(tsv[(size_t)(w1 & 0x1FFFF) * 8 + l]);
        float2 f2 = __half22float2(tsv[(size_t)(w2 & 0x1FFFF) * 8 + l]);
        float2 f3 = __half22float2(tsv[(size_t)(w3 & 0x1FFFF) * 8 + l]);
        sx += (f0.x + f1.x) + (f2.x + f3.x);
        sy += (f0.y + f1.y) + (f2.y + f3.y);
    }
    for (; i < e; ++i) {
        unsigned int w = ebuf2[i];
        float2 f = __half22float2(tsv[(size_t)(w & 0x1FFFF) * 8 + l]);
        sx += f.x; sy += f.y;
    }
    float2 sf = __half22float2(tsv[(size_t)v * 8 + l]);
    const float dv = dinv[v];
    h2v[(size_t)v * 8 + l] = __halves2half2(
        __float2half(dv * (sx + sf.x) + b2[2 * l]),
        __float2half(dv * (sy + sf.y) + b2[2 * l + 1]));
}

// ---- Edge scores (R8/R10-proven: 1 edge/thread, no NT) ----
__global__ void k_score(const int* __restrict__ row, const int* __restrict__ col,
                        const __half* __restrict__ h2h, float* __restrict__ out, int E) {
    int e = blockIdx.x * 256 + threadIdx.x;
    if (e < E) {
        union { uint4 u[2]; __half2 h[8]; } a, b;
        const uint4* pa = (const uint4*)(h2h + (size_t)row[e] * 16);
        const uint4* pb = (const uint4*)(h2h + (size_t)col[e] * 16);
        a.u[0] = pa[0]; a.u[1] = pa[1];
        b.u[0] = pb[0]; b.u[1] = pb[1];
        float d = 0.f;
        #pragma unroll
        for (int i = 0; i < 8; ++i) {
            float2 fa = __half22float2(a.h[i]);
            float2 fb = __half22float2(b.h[i]);
            d = fmaf(fa.x, fb.x, fmaf(fa.y, fb.y, d));
        }
        out[e] = 1.0f / (1.0f + __expf(-d));
    }
}

// ---------------- Fallback (R2 atomic path) ----------------
__global__ void k_countf(const int* __restrict__ col, float* __restrict__ deg, int E) {
    int e = blockIdx.x * 256 + threadIdx.x;
    if (e < E) atomicAdd(&deg[col[e]], 1.0f);
}
__global__ void k_dinvf(float* __restrict__ dinv, int N) {
    int v = blockIdx.x * 256 + threadIdx.x;
    if (v < N) dinv[v] = rsqrtf(dinv[v] + 1.0f);
}
__global__ __launch_bounds__(256) void k_gemm1f(
    const float* __restrict__ x, const float* __restrict__ W1,
    const float* __restrict__ dinv, float* __restrict__ ts, int N) {
    __shared__ float wsT[16 * 132];
    const int tid = threadIdx.x;
    for (int idx = tid; idx < 2048; idx += 256) {
        int k = idx >> 4, c = idx & 15;
        wsT[c * 132 + k] = W1[idx];
    }
    __syncthreads();
    const int n = blockIdx.x * 256 + tid;
    if (n >= N) return;
    const float4* xr = (const float4*)(x + (size_t)n * 128);
    float acc[16];
    #pragma unroll
    for (int c = 0; c < 16; ++c) acc[c] = 0.f;
    for (int k4 = 0; k4 < 32; ++k4) {
        float4 a = xr[k4];
        #pragma unroll
        for (int c = 0; c < 16; ++c) {
            const float4 w = *(const float4*)&wsT[c * 132 + k4 * 4];
            acc[c] = fmaf(a.x, w.x, fmaf(a.y, w.y, fmaf(a.z, w.z, fmaf(a.w, w.w, acc[c]))));
        }
    }
    float dv = dinv[n];
    float4* o = (float4*)(ts + (size_t)n * 16);
    #pragma unroll
    for (int q = 0; q < 4; ++q)
        o[q] = make_float4(acc[4*q] * dv, acc[4*q+1] * dv, acc[4*q+2] * dv, acc[4*q+3] * dv);
}
__global__ void k_scatter(const int* __restrict__ row, const int* __restrict__ col,
                          const float* __restrict__ ts, float* __restrict__ acc, int E) {
    int g = blockIdx.x * 256 + threadIdx.x;
    int e = g >> 4, c = g & 15;
    if (e < E) atomicAdd(&acc[(size_t)col[e] * 16 + c], ts[(size_t)row[e] * 16 + c]);
}
__global__ void k_finalize(float* __restrict__ acc, const float* __restrict__ ts,
                           const float* __restrict__ dinv, const float* __restrict__ b,
                           int N, int relu) {
    int g = blockIdx.x * 256 + threadIdx.x;
    int v = g >> 4, c = g & 15;
    if (v < N) {
        float h = dinv[v] * (acc[g] + ts[g]) + b[c];
        if (relu) h = fmaxf(h, 0.f);
        acc[g] = h;
    }
}
__global__ __launch_bounds__(256) void k_gemm2f(
    const float* __restrict__ h1, const float* __restrict__ W2,
    const float* __restrict__ dinv, float* __restrict__ ts2, int N) {
    __shared__ float hs[16 * 17];
    __shared__ float ws2[256];
    const int tid = threadIdx.x;
    const int base = blockIdx.x * 16;
    if (tid < 64) ((float4*)ws2)[tid] = ((const float4*)W2)[tid];
    if (tid >= 64 && tid < 128) {
        int t2 = tid - 64;
        float4 v4 = ((const float4*)(h1 + (size_t)base * 16))[t2];
        float* d = &hs[(t2 >> 2) * 17 + (t2 & 3) * 4];
        d[0] = v4.x; d[1] = v4.y; d[2] = v4.z; d[3] = v4.w;
    }
    __syncthreads();
    const int r = tid >> 4, c = tid & 15;
    float a = 0.f;
    #pragma unroll
    for (int kk = 0; kk < 16; ++kk) a = fmaf(hs[r * 17 + kk], ws2[kk * 16 + c], a);
    ts2[(size_t)(base + r) * 16 + c] = a * dinv[base + r];
}
__global__ void k_scoref(const int* __restrict__ row, const int* __restrict__ col,
                         const float* __restrict__ h2, float* __restrict__ out, int E) {
    int e = blockIdx.x * 256 + threadIdx.x;
    if (e < E) {
        const float4* a = (const float4*)(h2 + (size_t)row[e] * 16);
        const float4* b = (const float4*)(h2 + (size_t)col[e] * 16);
        float d = 0.f;
        #pragma unroll
        for (int i = 0; i < 4; ++i) {
            float4 u = a[i], v = b[i];
            d += u.x * v.x + u.y * v.y + u.z * v.z + u.w * v.w;
        }
        out[e] = 1.0f / (1.0f + __expf(-d));
    }
}

extern "C" void kernel_launch(void* const* d_in, const int* in_sizes, int n_in,
                              void* d_out, int out_size, void* d_ws, size_t ws_size,
                              hipStream_t stream) {
    const float* x  = (const float*)d_in[0];
    const int*   ei = (const int*)d_in[1];
    const float* W1 = (const float*)d_in[2];
    const float* b1 = (const float*)d_in[3];
    const float* W2 = (const float*)d_in[4];
    const float* b2 = (const float*)d_in[5];

    const int N = in_sizes[0] / 128;   // 100000
    const int E = in_sizes[1] / 2;     // 3200000
    const int* row = ei;
    const int* col = ei + E;
    float* out = (float*)d_out;

    const int NBUK = (N + BSZ - 1) / BSZ;          // 196
    const int CN = (E + MAXCH - 1) / MAXCH;        // 1000 chunks
    const int CH = MAXCH;                          // 3200, multiple of 4

    char* ws = (char*)d_ws;
    size_t off = 0;
    auto alloc = [&](size_t bytes) { void* p = ws + off; off += (bytes + 255) & ~(size_t)255; return p; };
    float*  dinv  = (float*)alloc((size_t)N * 4);
    __half* ts1h  = (__half*)alloc((size_t)N * 32);    // also h2h after pGat1
    __half* ts2h  = (__half*)alloc((size_t)N * 32);
    int*    start = (int*)alloc((size_t)(N + 1) * 4);
    int*    gcur  = (int*)alloc((size_t)NBUK * 4);
    unsigned int* ebuf  = (unsigned int*)alloc((size_t)NBUK * CAPB * 4);   // 25.7 MB
    unsigned int* ebuf2 = (unsigned int*)alloc((size_t)NBUK * CAPB * 4);   // 25.7 MB
    const size_t need = off;    // ~59 MB at N=100k, E=3.2M

    // fixed-capacity guard: uniform input fills buckets to ~CAPB/2 (+-128 sigma)
    if (N <= 131072 && NBUK <= 256 && CN <= MAXCHUNKS &&
        (size_t)E * 2 <= (size_t)NBUK * CAPB && ws_size >= need) {
        hipMemsetAsync(gcur, 0, (size_t)NBUK * 4, stream);
        pSort<<<CN, 512, 0, stream>>>(row, col, gcur, ebuf, E, CH, NBUK);
        pS2<<<NBUK, 1024, 0, stream>>>(ebuf, gcur, ebuf2, dinv, start, N);
        k_gemm1<<<(N + 255) / 256, 256, 0, stream>>>(x, W1, dinv, ts1h, N);
        pGat1<<<(N + 31) / 32, 256, 0, stream>>>(ebuf2, start, gcur, (const __half2*)ts1h,
                                                 dinv, b1, W2, (__half2*)ts2h, N);
        __half* h2h = ts1h;   // ts1h dead after pGat1
        pGat2<<<(N + 31) / 32, 256, 0, stream>>>(ebuf2, start, gcur, (const __half2*)ts2h,
                                                 dinv, b2, (__half2*)h2h, N);
        k_score<<<(E + 255) / 256, 256, 0, stream>>>(row, col, h2h, out, E);
    } else {
        // R2 fallback, fp32 buffers carved independently
        float* dinvF = (float*)ws;
        float* ts1F  = (float*)(ws + (size_t)N * 4);
        float* ts2F  = (float*)(ws + (size_t)N * 4 + (size_t)N * 64);
        hipMemsetAsync(dinvF, 0, (size_t)N * 4, stream);
        hipMemsetAsync(ts2F, 0, (size_t)N * 64, stream);
        k_countf<<<(E + 255) / 256, 256, 0, stream>>>(col, dinvF, E);
        k_dinvf<<<(N + 255) / 256, 256, 0, stream>>>(dinvF, N);
        k_gemm1f<<<(N + 255) / 256, 256, 0, stream>>>(x, W1, dinvF, ts1F, N);
        k_scatter<<<(E * 16) / 256, 256, 0, stream>>>(row, col, ts1F, ts2F, E);
        k_finalize<<<(N * 16 + 255) / 256, 256, 0, stream>>>(ts2F, ts1F, dinvF, b1, N, 1);
        k_gemm2f<<<N / 16, 256, 0, stream>>>(ts2F, W2, dinvF, ts1F, N);
        hipMemsetAsync(ts2F, 0, (size_t)N * 64, stream);
        k_scatter<<<(E * 16) / 256, 256, 0, stream>>>(row, col, ts1F, ts2F, E);
        k_finalize<<<(N * 16 + 255) / 256, 256, 0, stream>>>(ts2F, ts1F, dinvF, b2, N, 0);
        k_scoref<<<(E + 255) / 256, 256, 0, stream>>>(row, col, ts2F, out, E);
    }
}